// Round 4
// baseline (93.103 us; speedup 1.0000x reference)
//
#include <hip/hip_runtime.h>
#include <math.h>

typedef float f32x4 __attribute__((ext_vector_type(4)));

// Geometry (fixed by setup_inputs):
//   x: (16, 64, 64, 64) f32 ; sldj: (16,) ; a,b: (16, 32, 64, 64)
//   pi,mu,s: (16, 16, 32, 64, 64)  (B, K, Ch, H, W)
constexpr int NB = 16, NK = 16, NCh = 32, NH = 64, NW = 64;
constexpr int HW = NH * NW;                  // 4096
constexpr int PER_BATCH = NCh * HW;          // 131072
constexpr int NTOT = NB * PER_BATCH;         // 2097152
constexpr int PMS_BSTRIDE = NK * PER_BATCH;  // 2097152

__global__ void init_sldj_kernel(const float* __restrict__ sldj_in,
                                 float* __restrict__ out_sldj) {
    int i = threadIdx.x;
    if (i < NB) out_sldj[i] = sldj_in[i];
}

// Inline-asm load: issue is fixed in program order (volatile asm), completion
// tracked by US via counted vmcnt — the compiler cannot re-serialize this.
#define GLOAD4(dst, addr) \
    asm volatile("global_load_dwordx4 %0, %1, off" : "=v"(dst) : "v"(addr))

// Counted wait + scheduling fence (rule #18: sched_barrier stops hipcc from
// hoisting the dependent VALU above the waitcnt).
#define VMWAIT(N)                                              \
    do {                                                       \
        asm volatile("s_waitcnt vmcnt(" #N ")" ::: "memory");  \
        __builtin_amdgcn_sched_barrier(0);                     \
    } while (0)

// Issue one chunk of 4 k-steps (12 dwordx4 loads) into buffer `buf`.
#define ISSUE(buf, kbase)                                                     \
    do {                                                                      \
        _Pragma("unroll") for (int j = 0; j < 4; ++j) {                       \
            GLOAD4(Pb[buf][j], pp + (size_t)((kbase) + j) * PER_BATCH);       \
            GLOAD4(Mb[buf][j], mp + (size_t)((kbase) + j) * PER_BATCH);       \
            GLOAD4(Sb[buf][j], sp + (size_t)((kbase) + j) * PER_BATCH);       \
        }                                                                     \
    } while (0)

// Consume buffer `buf` (4 k-steps x 4 elems), max-free single-pass sums.
#define COMPUTE(buf)                                                          \
    do {                                                                      \
        _Pragma("unroll") for (int j = 0; j < 4; ++j) {                       \
            _Pragma("unroll") for (int e = 0; e < 4; ++e) {                   \
                const float es = __expf(-Sb[buf][j][e]);                      \
                float z = (x4[e] - Mb[buf][j][e]) * es;                       \
                z = fmaxf(z, -87.0f); /* keep exp(-z) finite */               \
                const float t   = __expf(-z);                                 \
                const float sig = __builtin_amdgcn_rcpf(1.0f + t);            \
                const float ep  = __expf(Pb[buf][j][e]);                      \
                const float epc = ep * sig;                                   \
                const float cc  = epc * t;                                    \
                sumw[e]  += ep;                                               \
                scdf[e]  += epc;                                              \
                sccdf[e] += cc;                                               \
                spdf[e]   = fmaf(cc, sig * es, spdf[e]);                      \
            }                                                                 \
        }                                                                     \
    } while (0)

__launch_bounds__(256)
__global__ void mixlogcdf_kernel(const float* __restrict__ x,
                                 const float* __restrict__ a,
                                 const float* __restrict__ b,
                                 const float* __restrict__ pi,
                                 const float* __restrict__ mu,
                                 const float* __restrict__ s,
                                 float* __restrict__ out,
                                 float* __restrict__ out_sldj) {
    const int tid   = blockIdx.x * 256 + threadIdx.x;  // [0, NTOT/4)
    const int gid   = tid << 2;                        // first of 4 elems
    const int batch = gid >> 17;                       // / PER_BATCH
    const int rem   = gid & (PER_BATCH - 1);
    const int xbase = (batch << 18) | rem;             // into x/out (change half)

    const size_t base = (size_t)batch * PMS_BSTRIDE + rem;
    const float* pp = pi + base;
    const float* mp = mu + base;
    const float* sp = s + base;

    // All input loads are asm: the only vmcnt traffic in the pipeline is ours.
    f32x4 x4, a4, b4, id4;
    GLOAD4(x4, x + xbase);
    GLOAD4(a4, a + gid);
    GLOAD4(b4, b + gid);
    GLOAD4(id4, x + xbase + PER_BATCH);   // 4 outstanding

    f32x4 Pb[2][4], Mb[2][4], Sb[2][4];
    ISSUE(0, 0);   // 16 outstanding
    ISSUE(1, 4);   // 28 outstanding

    float sumw[4]  = {0.f, 0.f, 0.f, 0.f};
    float scdf[4]  = {0.f, 0.f, 0.f, 0.f};
    float sccdf[4] = {0.f, 0.f, 0.f, 0.f};
    float spdf[4]  = {0.f, 0.f, 0.f, 0.f};

    VMWAIT(12);        // {x,a,b,id} + chunk0 complete; chunk1 in flight
    COMPUTE(0);
    ISSUE(0, 8);       // 24 outstanding
    VMWAIT(12);        // chunk1 complete
    COMPUTE(1);
    ISSUE(1, 12);      // 24 outstanding
    VMWAIT(12);        // chunk2 complete
    COMPUTE(0);
    VMWAIT(0);         // chunk3 complete
    COMPUTE(1);

    f32x4 o4;
    float srow = 0.f;
#pragma unroll
    for (int e = 0; e < 4; ++e) {
        const float lsp  = __logf(sumw[e]);
        const float lsc  = __logf(fmaxf(scdf[e], 1e-37f));
        const float lscc = __logf(fmaxf(sccdf[e], 1e-37f));
        const float lst  = __logf(fmaxf(spdf[e], 1e-37f));
        // out_pre = log u - log1p(-u) = lsc - lscc
        o4[e] = (lsc - lscc + b4[e]) * __expf(a4[e]);
        // logistic_ldj + scale_ldj + a = (lst - lsp) + (2*lsp - lsc - lscc) + a
        srow += lst + lsp - lsc - lscc + a4[e];
    }
    *(f32x4*)(out + xbase) = o4;
    *(f32x4*)(out + xbase + PER_BATCH) = id4;  // identity half passthrough

    // Per-batch sldj reduction (block's 1024 elems lie in one batch).
#pragma unroll
    for (int off = 32; off > 0; off >>= 1) srow += __shfl_down(srow, off, 64);
    __shared__ float wsum[4];
    const int lane = threadIdx.x & 63;
    const int wid  = threadIdx.x >> 6;
    if (lane == 0) wsum[wid] = srow;
    __syncthreads();
    if (threadIdx.x == 0) {
        atomicAdd(&out_sldj[batch], wsum[0] + wsum[1] + wsum[2] + wsum[3]);
    }
}

extern "C" void kernel_launch(void* const* d_in, const int* in_sizes, int n_in,
                              void* d_out, int out_size, void* d_ws, size_t ws_size,
                              hipStream_t stream) {
    const float* x    = (const float*)d_in[0];
    const float* sldj = (const float*)d_in[1];
    const float* a    = (const float*)d_in[2];
    const float* b    = (const float*)d_in[3];
    const float* pi   = (const float*)d_in[4];
    const float* mu   = (const float*)d_in[5];
    const float* s    = (const float*)d_in[6];

    float* out      = (float*)d_out;
    float* out_sldj = out + (size_t)NB * 2 * PER_BATCH;

    init_sldj_kernel<<<1, 64, 0, stream>>>(sldj, out_sldj);
    mixlogcdf_kernel<<<NTOT / 1024, 256, 0, stream>>>(x, a, b, pi, mu, s, out, out_sldj);
}

// Round 5
// 88.951 us; speedup vs baseline: 1.0467x; 1.0467x over previous
//
#include <hip/hip_runtime.h>
#include <math.h>

typedef float f32x4 __attribute__((ext_vector_type(4)));

// Geometry (fixed by setup_inputs):
//   x: (16, 64, 64, 64) f32 ; sldj: (16,) ; a,b: (16, 32, 64, 64)
//   pi,mu,s: (16, 16, 32, 64, 64)  (B, K, Ch, H, W)
constexpr int NB = 16, NK = 16, NCh = 32, NH = 64, NW = 64;
constexpr int HW = NH * NW;                  // 4096
constexpr int PER_BATCH = NCh * HW;          // 131072
constexpr int NTOT = NB * PER_BATCH;         // 2097152
constexpr int PMS_BSTRIDE = NK * PER_BATCH;  // 2097152
constexpr int TILE = 1024;                   // 256 threads * 4 elems
constexpr int NTILES = NTOT / TILE;          // 2048
constexpr int NBLOCKS = 1024;                // exactly 4 blocks/CU resident
constexpr int TPB = NTILES / NBLOCKS;        // 2 contiguous tiles per block

// Inline-asm load: issue order fixed (volatile asm); completion tracked by
// counted vmcnt — compiler cannot re-serialize the pipeline.
#define GLOAD4(dst, addr) \
    asm volatile("global_load_dwordx4 %0, %1, off" : "=v"(dst) : "v"(addr))

#define VMWAIT(N)                                              \
    do {                                                       \
        asm volatile("s_waitcnt vmcnt(" #N ")" ::: "memory");  \
        __builtin_amdgcn_sched_barrier(0);                     \
    } while (0)

// Issue one chunk of 4 k-steps (12 dwordx4 loads) into buffer `buf`.
#define ISSUE(buf, kbase)                                                     \
    do {                                                                      \
        _Pragma("unroll") for (int j = 0; j < 4; ++j) {                       \
            GLOAD4(Pb[buf][j], pp + (size_t)((kbase) + j) * PER_BATCH);       \
            GLOAD4(Mb[buf][j], mp + (size_t)((kbase) + j) * PER_BATCH);       \
            GLOAD4(Sb[buf][j], sp + (size_t)((kbase) + j) * PER_BATCH);       \
        }                                                                     \
    } while (0)

// Consume buffer `buf` (4 k-steps x 4 elems), max-free single-pass sums.
#define COMPUTE(buf)                                                          \
    do {                                                                      \
        _Pragma("unroll") for (int j = 0; j < 4; ++j) {                       \
            _Pragma("unroll") for (int e = 0; e < 4; ++e) {                   \
                const float es = __expf(-Sb[buf][j][e]);                      \
                float z = (x4[e] - Mb[buf][j][e]) * es;                       \
                z = fmaxf(z, -87.0f); /* keep exp(-z) finite */               \
                const float t   = __expf(-z);                                 \
                const float sig = __builtin_amdgcn_rcpf(1.0f + t);            \
                const float ep  = __expf(Pb[buf][j][e]);                      \
                const float epc = ep * sig;                                   \
                const float cc  = epc * t;                                    \
                sumw[e]  += ep;                                               \
                scdf[e]  += epc;                                              \
                sccdf[e] += cc;                                               \
                spdf[e]   = fmaf(cc, sig * es, spdf[e]);                      \
            }                                                                 \
        }                                                                     \
    } while (0)

__launch_bounds__(256)
__global__ void mixlogcdf_kernel(const float* __restrict__ x,
                                 const float* __restrict__ a,
                                 const float* __restrict__ b,
                                 const float* __restrict__ pi,
                                 const float* __restrict__ mu,
                                 const float* __restrict__ s,
                                 float* __restrict__ out,
                                 float* __restrict__ ws) {
    const int blk = blockIdx.x;  // [0, 1024); both tiles in one batch (64 blk/batch)
    float srow = 0.f;            // per-thread ldj partial across both tiles

    for (int t = 0; t < TPB; ++t) {
        const int tile  = blk * TPB + t;
        const int gid   = tile * TILE + (threadIdx.x << 2);
        const int batch = gid >> 17;
        const int rem   = gid & (PER_BATCH - 1);
        const int xbase = (batch << 18) | rem;

        const size_t base = (size_t)batch * PMS_BSTRIDE + rem;
        const float* pp = pi + base;
        const float* mp = mu + base;
        const float* sp = s + base;

        f32x4 x4, a4, b4, id4;
        GLOAD4(x4, x + xbase);
        GLOAD4(a4, a + gid);
        GLOAD4(b4, b + gid);
        GLOAD4(id4, x + xbase + PER_BATCH);

        f32x4 Pb[2][4], Mb[2][4], Sb[2][4];
        ISSUE(0, 0);   // 16 outstanding
        ISSUE(1, 4);   // 28 outstanding

        float sumw[4]  = {0.f, 0.f, 0.f, 0.f};
        float scdf[4]  = {0.f, 0.f, 0.f, 0.f};
        float sccdf[4] = {0.f, 0.f, 0.f, 0.f};
        float spdf[4]  = {0.f, 0.f, 0.f, 0.f};

        VMWAIT(12);    // prologue + chunk0 done; chunk1 in flight
        COMPUTE(0);
        ISSUE(0, 8);
        VMWAIT(12);    // chunk1 done
        COMPUTE(1);
        ISSUE(1, 12);
        VMWAIT(12);    // chunk2 done
        COMPUTE(0);
        VMWAIT(0);     // chunk3 done
        COMPUTE(1);

        f32x4 o4;
#pragma unroll
        for (int e = 0; e < 4; ++e) {
            const float lsp  = __logf(sumw[e]);
            const float lsc  = __logf(fmaxf(scdf[e], 1e-37f));
            const float lscc = __logf(fmaxf(sccdf[e], 1e-37f));
            const float lst  = __logf(fmaxf(spdf[e], 1e-37f));
            // out_pre = log u - log1p(-u) = lsc - lscc
            o4[e] = (lsc - lscc + b4[e]) * __expf(a4[e]);
            // logistic_ldj + scale_ldj + a
            srow += lst + lsp - lsc - lscc + a4[e];
        }
        *(f32x4*)(out + xbase) = o4;
        *(f32x4*)(out + xbase + PER_BATCH) = id4;  // identity passthrough
    }

    // Block reduction of srow (both tiles, same batch) -> ws[blk]. No atomics.
#pragma unroll
    for (int off = 32; off > 0; off >>= 1) srow += __shfl_down(srow, off, 64);
    __shared__ float wsum[4];
    const int lane = threadIdx.x & 63;
    const int wid  = threadIdx.x >> 6;
    if (lane == 0) wsum[wid] = srow;
    __syncthreads();
    if (threadIdx.x == 0) ws[blk] = wsum[0] + wsum[1] + wsum[2] + wsum[3];
}

// Final: out_sldj[b] = sldj_in[b] + sum of that batch's 64 block partials.
__global__ void sldj_reduce_kernel(const float* __restrict__ sldj_in,
                                   const float* __restrict__ ws,
                                   float* __restrict__ out_sldj) {
    const int bb = blockIdx.x;  // [0, NB)
    float v = ws[bb * 64 + threadIdx.x];
#pragma unroll
    for (int off = 32; off > 0; off >>= 1) v += __shfl_down(v, off, 64);
    if (threadIdx.x == 0) out_sldj[bb] = sldj_in[bb] + v;
}

extern "C" void kernel_launch(void* const* d_in, const int* in_sizes, int n_in,
                              void* d_out, int out_size, void* d_ws, size_t ws_size,
                              hipStream_t stream) {
    const float* x    = (const float*)d_in[0];
    const float* sldj = (const float*)d_in[1];
    const float* a    = (const float*)d_in[2];
    const float* b    = (const float*)d_in[3];
    const float* pi   = (const float*)d_in[4];
    const float* mu   = (const float*)d_in[5];
    const float* s    = (const float*)d_in[6];

    float* out      = (float*)d_out;
    float* out_sldj = out + (size_t)NB * 2 * PER_BATCH;
    float* wsf      = (float*)d_ws;  // 1024 floats, fully rewritten every call

    mixlogcdf_kernel<<<NBLOCKS, 256, 0, stream>>>(x, a, b, pi, mu, s, out, wsf);
    sldj_reduce_kernel<<<NB, 64, 0, stream>>>(sldj, wsf, out_sldj);
}